// Round 8
// baseline (349.174 us; speedup 1.0000x reference)
//
#include <hip/hip_runtime.h>
#include <hip/hip_bf16.h>
#include <stdint.h>

// MoE top-2 of 8 experts.  B=2,T=1024 -> nt=2048 tokens, D=1024, H=4096, E=8.
// d_out layout: out[2*1024*1024] f32 | gate_value[2048*8] f32 | lb_loss[1] f32.
//
// R8: f32-direct weights (no conv passes), with the R7 bug fixed:
// B register stage is 2-deep CROSS-iteration (bregA/bregB, unroll-2 so all
// indices static), issue order B-then-A so the compiler's breg wait is
// vmcnt(8) (leaves A + next group in flight), ring-3 LDS, raw s_barrier,
// counted vmcnt(6) at iter top.  vmcnt never 0 in steady state (T4).
// Swizzles carried from R5/R7 (both measured 0 bank conflicts).

#define NTOK 2048
#define DDIM 1024
#define HDIM 4096
#define NEXP 8
#define KSPLIT 2

typedef float  f32x4  __attribute__((ext_vector_type(4)));
typedef __bf16 bf16x8 __attribute__((ext_vector_type(8)));
typedef __bf16 bf16x4 __attribute__((ext_vector_type(4)));

typedef const __attribute__((address_space(1))) void g1_t;
typedef __attribute__((address_space(3))) void l3_t;
__device__ __forceinline__ void gld16(const void* g, void* l) {
  // async global->LDS, 16B/lane; LDS dest = wave-uniform base + lane*16
  __builtin_amdgcn_global_load_lds((g1_t*)g, (l3_t*)l, 16, 0, 0);
}

// ---------------- init: zero the fill counters ----------------
__global__ void init_kernel(int* fill) {
  int t = threadIdx.x;
  if (t < NEXP) fill[t] = 0;
}

// ---------------- zero ybuf (gemm2 accumulates with atomics) ----------------
__global__ __launch_bounds__(256)
void zero_y_kernel(float* __restrict__ y) {
  size_t i = (size_t)blockIdx.x * 256 + threadIdx.x;
  ((f32x4*)y)[i] = (f32x4){0.f, 0.f, 0.f, 0.f};
}

// ---------------- gate: logits, softmax, top2; emits xbf.  NO atomics. ----------------
__global__ __launch_bounds__(256)
void gate_kernel(const float* __restrict__ x, const unsigned char* __restrict__ pmask,
                 const float* __restrict__ Wg, float* __restrict__ gate_out,
                 int* __restrict__ tix, float* __restrict__ twt,
                 __bf16* __restrict__ xbf)
{
  int wave = threadIdx.x >> 6, lane = threadIdx.x & 63;
  int t = blockIdx.x * 4 + wave;   // one wave per token
  const f32x4* x4 = (const f32x4*)(x + (size_t)t * DDIM);
  const f32x4* w4 = (const f32x4*)Wg;
  bf16x4* xb4 = (bf16x4*)(xbf + (size_t)t * DDIM);
  float acc[NEXP];
#pragma unroll
  for (int e = 0; e < NEXP; ++e) acc[e] = 0.f;
#pragma unroll
  for (int i = 0; i < 4; ++i) {
    f32x4 xv = x4[i * 64 + lane];
    bf16x4 xo;
#pragma unroll
    for (int q = 0; q < 4; ++q) xo[q] = (__bf16)xv[q];
    xb4[i * 64 + lane] = xo;
#pragma unroll
    for (int e = 0; e < NEXP; ++e) {
      f32x4 wv = w4[e * 256 + i * 64 + lane];
      acc[e] += xv[0]*wv[0] + xv[1]*wv[1] + xv[2]*wv[2] + xv[3]*wv[3];
    }
  }
#pragma unroll
  for (int e = 0; e < NEXP; ++e) {
    float v = acc[e];
#pragma unroll
    for (int off = 32; off > 0; off >>= 1) v += __shfl_xor(v, off, 64);
    acc[e] = v;
  }
  if (lane == 0) {
    bool pm = pmask[t] != 0;
    float m = acc[0];
#pragma unroll
    for (int e = 1; e < NEXP; ++e) m = fmaxf(m, acc[e]);
    float g[NEXP]; float s = 0.f;
#pragma unroll
    for (int e = 0; e < NEXP; ++e) { g[e] = expf(acc[e] - m); s += g[e]; }
    float inv = 1.f / s;
#pragma unroll
    for (int e = 0; e < NEXP; ++e) g[e] *= inv;
    if (pm) {
#pragma unroll
      for (int e = 0; e < NEXP; ++e) g[e] = 0.f;
    }
    int i1 = 0;
#pragma unroll
    for (int e = 1; e < NEXP; ++e) if (g[e] > g[i1]) i1 = e;
    int i2 = -1;
#pragma unroll
    for (int e = 0; e < NEXP; ++e) if (e != i1 && (i2 < 0 || g[e] > g[i2])) i2 = e;
    float w1 = g[i1], w2 = g[i2], ss = w1 + w2;
    if (ss == 0.f) ss = 1.f;
    w1 /= ss; w2 /= ss;
#pragma unroll
    for (int e = 0; e < NEXP; ++e) gate_out[(size_t)t * NEXP + e] = g[e];
    tix[2*t] = i1; tix[2*t+1] = i2;
    twt[2*t] = w1; twt[2*t+1] = w2;
  }
}

// ---------------- stats: single-block tree reduce -> ecount/offs/lb ----------------
__global__ __launch_bounds__(1024)
void stats_kernel(const float* __restrict__ gate_out, const int* __restrict__ tix,
                  const unsigned char* __restrict__ pmask,
                  int* __restrict__ ecount, int* __restrict__ offs,
                  float* __restrict__ lb_out)
{
  int tid = threadIdx.x, lane = tid & 63, wv = tid >> 6;   // 16 waves
  float lg[NEXP]; float lt1[NEXP]; int lec[NEXP]; float ln = 0.f;
#pragma unroll
  for (int e = 0; e < NEXP; ++e) { lg[e] = 0.f; lt1[e] = 0.f; lec[e] = 0; }
#pragma unroll
  for (int it = 0; it < NTOK / 1024; ++it) {
    int t = tid + it * 1024;
    f32x4 g0 = ((const f32x4*)(gate_out + (size_t)t * NEXP))[0];
    f32x4 g1 = ((const f32x4*)(gate_out + (size_t)t * NEXP))[1];
    lg[0] += g0[0]; lg[1] += g0[1]; lg[2] += g0[2]; lg[3] += g0[3];
    lg[4] += g1[0]; lg[5] += g1[1]; lg[6] += g1[2]; lg[7] += g1[3];
    if (!pmask[t]) {
      int i1 = tix[2*t], i2 = tix[2*t+1];
      lt1[i1] += 1.f; lec[i1] += 1; lec[i2] += 1; ln += 1.f;
    }
  }
#pragma unroll
  for (int e = 0; e < NEXP; ++e) {
#pragma unroll
    for (int off = 32; off > 0; off >>= 1) {
      lg[e]  += __shfl_xor(lg[e],  off, 64);
      lt1[e] += __shfl_xor(lt1[e], off, 64);
      lec[e] += __shfl_xor(lec[e], off, 64);
    }
  }
#pragma unroll
  for (int off = 32; off > 0; off >>= 1) ln += __shfl_xor(ln, off, 64);
  __shared__ float sg[16][NEXP], st[16][NEXP], sn[16];
  __shared__ int   se[16][NEXP];
  if (lane == 0) {
#pragma unroll
    for (int e = 0; e < NEXP; ++e) { sg[wv][e] = lg[e]; st[wv][e] = lt1[e]; se[wv][e] = lec[e]; }
    sn[wv] = ln;
  }
  __syncthreads();
  if (tid == 0) {
    float G[NEXP] = {0}, T1[NEXP] = {0}; int EC[NEXP] = {0}; float N = 0.f;
    for (int w = 0; w < 16; ++w) {
      N += sn[w];
#pragma unroll
      for (int e = 0; e < NEXP; ++e) { G[e] += sg[w][e]; T1[e] += st[w][e]; EC[e] += se[w][e]; }
    }
    int o = 0;
    for (int e = 0; e < NEXP; ++e) { ecount[e] = EC[e]; offs[e] = o; o += EC[e]; }
    if (N <= 0.f) N = 1.f;
    float lb = 0.f;
    for (int e = 0; e < NEXP; ++e) lb += (T1[e] / N) * (G[e] / N);
    lb_out[0] = (float)NEXP * lb;
  }
}

// ---------------- compaction: ballot-aggregated (1 atomic/wave/expert) ----------------
__global__ __launch_bounds__(256)
void compact_kernel(const unsigned char* __restrict__ pmask, const int* __restrict__ tix,
                    const int* __restrict__ offs, int* __restrict__ fill,
                    int* __restrict__ tok_list, int* __restrict__ slot_of)
{
  int t = blockIdx.x * 256 + threadIdx.x;
  int lane = threadIdx.x & 63;
  bool pm = pmask[t] != 0;
#pragma unroll
  for (int j = 0; j < 2; ++j) {
    int e = pm ? -1 : tix[2*t + j];
    int pos = -1;
#pragma unroll
    for (int ex = 0; ex < NEXP; ++ex) {
      unsigned long long mask = __ballot(e == ex);
      if (mask) {
        int leader = (int)(__ffsll((long long)mask) - 1);
        int base = 0;
        if (lane == leader) base = atomicAdd(&fill[ex], (int)__popcll(mask));
        base = __shfl(base, leader, 64);
        if (e == ex)
          pos = offs[ex] + base + (int)__popcll(mask & ((1ull << lane) - 1ull));
      }
    }
    if (e >= 0) { tok_list[pos] = t; slot_of[2*t + j] = pos; }
    else slot_of[2*t + j] = -1;
  }
}

// ======================= GEMM cores (R8) =======================
// 128x128 tile, BK=32, ring-3 LDS (48KB), 4 waves (2x2), mfma 16x16x32.
// A (bf16): gld16, linear dest, source pre-swizzled (chunk^((row>>1)&3)).
// B (f32 weights): per-iter issue [B-loads x4 THEN A gld16 x2] for tile
//   t+2; write B(t+1) (loaded one iter ago) after MFMA(t).  FIFO: breg use
//   waits vmcnt(8); iter-top vmcnt(6) = A(t) done.  lgkmcnt(0) before each
//   barrier for ds_write visibility.  Never vmcnt(0) except the tail.
// B thread map (R7, conflict-free): q=0..3: row r=(tid>>3)+32q, half
//   h=tid&1 of 16B chunk cd=(tid&7)>>1 -> LDS elem r*32+((cd^s(r))<<3)+h*4.
// Fragment-read undo: cg = ((lane>>4) ^ ((lane>>1)&3))*8.

#define B_LOAD(REG, koff)                                              \
  _Pragma("unroll")                                                    \
  for (int q = 0; q < 4; ++q) REG[q] = *(const f32x4*)(bp[q] + (koff));

#define B_WRITE(dst, REG)                                              \
  _Pragma("unroll")                                                    \
  for (int q = 0; q < 4; ++q) {                                        \
    bf16x4 o;                                                          \
    o[0] = (__bf16)REG[q][0]; o[1] = (__bf16)REG[q][1];                \
    o[2] = (__bf16)REG[q][2]; o[3] = (__bf16)REG[q][3];                \
    *(bf16x4*)&(dst)[bwofs[q]] = o;                                    \
  }

#define FRAG_MFMA(cur)                                                               \
  {                                                                                  \
    bf16x8 af[4], bfr[4];                                                            \
    _Pragma("unroll")                                                                \
    for (int m = 0; m < 4; ++m)                                                      \
      af[m]  = *(const bf16x8*)&As[cur][(wm*64 + m*16 + (lane & 15)) * 32 + cg];     \
    _Pragma("unroll")                                                                \
    for (int n = 0; n < 4; ++n)                                                      \
      bfr[n] = *(const bf16x8*)&Bs[cur][(wn*64 + n*16 + (lane & 15)) * 32 + cg];     \
    _Pragma("unroll")                                                                \
    for (int m = 0; m < 4; ++m)                                                      \
      _Pragma("unroll")                                                              \
      for (int n = 0; n < 4; ++n)                                                    \
        acc[m][n] = __builtin_amdgcn_mfma_f32_16x16x32_bf16(af[m], bfr[n], acc[m][n], 0, 0, 0); \
  }

#define GITER(t, NITc, WREG, LREG)                                     \
  {                                                                    \
    if ((t) == (NITc) - 1) asm volatile("s_waitcnt vmcnt(0)" ::: "memory"); \
    else                   asm volatile("s_waitcnt vmcnt(6)" ::: "memory"); \
    __builtin_amdgcn_s_barrier();                                      \
    __builtin_amdgcn_sched_barrier(0);                                 \
    if ((t) + 2 < (NITc)) {                                            \
      int k2 = kb0 + ((t) + 2) * 32;                                   \
      B_LOAD(LREG, k2)                                                 \
      int nb = ((t) + 2) % 3;                                          \
      gld16(aP[0] + k2, &As[nb][wave * 512]);                          \
      gld16(aP[1] + k2, &As[nb][2048 + wave * 512]);                   \
    }                                                                  \
    FRAG_MFMA((t) % 3)                                                 \
    if ((t) + 1 < (NITc)) {                                            \
      B_WRITE(Bs[((t) + 1) % 3], WREG)                                 \
      asm volatile("s_waitcnt lgkmcnt(0)" ::: "memory");               \
    }                                                                  \
  }

// ---------------- GEMM1: h[slot,:] = relu(xbf[tok]·W1[e]^T + b1[e]) ----------------
__global__ __launch_bounds__(256)
void gemm1_kernel(const __bf16* __restrict__ xbf, const float* __restrict__ W1,
                  const float* __restrict__ b1, const int* __restrict__ ecount,
                  const int* __restrict__ offs, const int* __restrict__ tok_list,
                  __bf16* __restrict__ hbuf)
{
  const int NTILE = HDIM / 128;   // 32
  const int MTILE = NTOK / 128;   // 16
  int bid = blockIdx.x;
  int e = bid / (MTILE * NTILE);
  int rem = bid % (MTILE * NTILE);
  int mt = rem / NTILE, nt = rem % NTILE;
  int cnt = ecount[e];
  if (mt * 128 >= cnt) return;
  int off = offs[e];

  __shared__ __bf16 As[3][128 * 32];
  __shared__ __bf16 Bs[3][128 * 32];

  int tid = threadIdx.x, lane = tid & 63, wave = tid >> 6;
  int wm = wave >> 1, wn = wave & 1;

  const __bf16* aP[2];
#pragma unroll
  for (int c = 0; c < 2; ++c) {
    int row = c * 64 + (tid >> 2);
    int cd = (tid & 3) ^ ((row >> 1) & 3);
    int mrow = mt * 128 + row;
    int tok = tok_list[off + ((mrow < cnt) ? mrow : 0)];
    aP[c] = xbf + (size_t)tok * DDIM + cd * 8;
  }
  const float* bp[4];
  int bwofs[4];
#pragma unroll
  for (int q = 0; q < 4; ++q) {
    int r = (tid >> 3) + 32 * q;
    bp[q] = W1 + (size_t)e * HDIM * DDIM + (size_t)(nt * 128 + r) * DDIM + (tid & 7) * 4;
    int cd = (tid & 7) >> 1, h = tid & 1;
    bwofs[q] = r * 32 + ((cd ^ ((r >> 1) & 3)) << 3) + h * 4;
  }
  int cg = ((lane >> 4) ^ ((lane >> 1) & 3)) << 3;

  f32x4 acc[4][4];
#pragma unroll
  for (int m = 0; m < 4; ++m)
#pragma unroll
    for (int n = 0; n < 4; ++n) acc[m][n] = (f32x4){0.f, 0.f, 0.f, 0.f};

  const int NIT = DDIM / 32;   // 32 (even)
  const int kb0 = 0;
  f32x4 bregA[4], bregB[4];
  // prologue: group(0) = [B(0), A(0)], group(1) = [B(1), A(1)]
  B_LOAD(bregA, 0)
  gld16(aP[0], &As[0][wave * 512]);
  gld16(aP[1], &As[0][2048 + wave * 512]);
  B_LOAD(bregB, 32)
  gld16(aP[0] + 32, &As[1][wave * 512]);
  gld16(aP[1] + 32, &As[1][2048 + wave * 512]);
  B_WRITE(Bs[0], bregA)            // compiler waits vmcnt(8) = B(0) done
  asm volatile("s_waitcnt lgkmcnt(0)" ::: "memory");

  for (int tt = 0; tt < NIT; tt += 2) {
    GITER(tt,     NIT, bregB, bregA)
    GITER(tt + 1, NIT, bregA, bregB)
  }

  // epilogue: +bias, relu, bf16 store
#pragma unroll
  for (int n = 0; n < 4; ++n) {
    int col = nt * 128 + wn * 64 + n * 16 + (lane & 15);
    float bias = b1[e * HDIM + col];
#pragma unroll
    for (int m = 0; m < 4; ++m) {
#pragma unroll
      for (int j = 0; j < 4; ++j) {
        int mr = mt * 128 + wm * 64 + m * 16 + ((lane >> 4) << 2) + j;
        if (mr < cnt) {
          float v = fmaxf(acc[m][n][j] + bias, 0.f);
          hbuf[(size_t)(off + mr) * HDIM + col] = (__bf16)v;
        }
      }
    }
  }
}

// ---------------- GEMM2 (K-split): ybuf[slot,:] += hbuf[slot]·W2[e]^T ----------------
__global__ __launch_bounds__(256)
void gemm2_kernel(const __bf16* __restrict__ hbuf, const float* __restrict__ W2,
                  const int* __restrict__ ecount, const int* __restrict__ offs,
                  float* __restrict__ ybuf)
{
  const int NTILE = DDIM / 128;   // 8
  const int MTILE = NTOK / 128;   // 16
  int bid = blockIdx.x;
  int e = bid / (MTILE * NTILE * KSPLIT);
  int rem = bid % (MTILE * NTILE * KSPLIT);
  int mt = rem / (NTILE * KSPLIT);
  int rem2 = rem % (NTILE * KSPLIT);
  int nt = rem2 / KSPLIT, kc = rem2 % KSPLIT;
  int cnt = ecount[e];
  if (mt * 128 >= cnt) return;
  int off = offs[e];

  __shared__ __bf16 As[3][128 * 32];
  __shared__ __bf16 Bs[3][128 * 32];

  int tid = threadIdx.x, lane = tid & 63, wave = tid >> 6;
  int wm = wave >> 1, wn = wave & 1;

  const __bf16* aP[2];
#pragma unroll
  for (int c = 0; c < 2; ++c) {
    int row = c * 64 + (tid >> 2);
    int cd = (tid & 3) ^ ((row >> 1) & 3);
    aP[c] = hbuf + (size_t)(off + mt * 128 + row) * HDIM + cd * 8;
  }
  const float* bp[4];
  int bwofs[4];
#pragma unroll
  for (int q = 0; q < 4; ++q) {
    int r = (tid >> 3) + 32 * q;
    bp[q] = W2 + (size_t)e * DDIM * HDIM + (size_t)(nt * 128 + r) * HDIM + (tid & 7) * 4;
    int cd = (tid & 7) >> 1, h = tid & 1;
    bwofs[q] = r * 32 + ((cd ^ ((r >> 1) & 3)) << 3) + h * 4;
  }
  int cg = ((lane >> 4) ^ ((lane >> 1) & 3)) << 3;

  f32x4 acc[4][4];
#pragma unroll
  for (int m = 0; m < 4; ++m)
#pragma unroll
    for (int n = 0; n < 4; ++n) acc[m][n] = (f32x4){0.f, 0.f, 0.f, 0.f};

  const int NIT = (HDIM / KSPLIT) / 32;   // 64 (even)
  const int kb0 = kc * (HDIM / KSPLIT);
  f32x4 bregA[4], bregB[4];
  B_LOAD(bregA, kb0)
  gld16(aP[0] + kb0, &As[0][wave * 512]);
  gld16(aP[1] + kb0, &As[0][2048 + wave * 512]);
  B_LOAD(bregB, kb0 + 32)
  gld16(aP[0] + kb0 + 32, &As[1][wave * 512]);
  gld16(aP[1] + kb0 + 32, &As[1][2048 + wave * 512]);
  B_WRITE(Bs[0], bregA)
  asm volatile("s_waitcnt lgkmcnt(0)" ::: "memory");

  for (int tt = 0; tt < NIT; tt += 2) {
    GITER(tt,     NIT, bregB, bregA)
    GITER(tt + 1, NIT, bregA, bregB)
  }

  // epilogue: atomic accumulate raw partials (bias+gate weight in combine)
#pragma unroll
  for (int m = 0; m < 4; ++m) {
#pragma unroll
    for (int j = 0; j < 4; ++j) {
      int mr = mt * 128 + wm * 64 + m * 16 + ((lane >> 4) << 2) + j;
      if (mr >= cnt) continue;
      int slot = off + mr;
#pragma unroll
      for (int n = 0; n < 4; ++n) {
        int col = nt * 128 + wn * 64 + n * 16 + (lane & 15);
        atomicAdd(&ybuf[(size_t)slot * DDIM + col], acc[m][n][j]);
      }
    }
  }
}

// ---------------- combine: out[t] = wA*(y[sA]+b2[eA]) + wB*(y[sB]+b2[eB]) ----------------
__global__ __launch_bounds__(256)
void combine_kernel(const float* __restrict__ ybuf, const int* __restrict__ slot_of,
                    const int* __restrict__ tix, const float* __restrict__ twt,
                    const float* __restrict__ b2, float* __restrict__ out)
{
  int t = blockIdx.x;
  int d4 = threadIdx.x;
  int sA = slot_of[2*t], sB = slot_of[2*t + 1];
  f32x4 r = (f32x4){0.f, 0.f, 0.f, 0.f};
  if (sA >= 0) {
    float wA = twt[2*t];
    f32x4 y = ((const f32x4*)(ybuf + (size_t)sA * DDIM))[d4];
    f32x4 b = ((const f32x4*)(b2 + (size_t)tix[2*t] * DDIM))[d4];
    r += wA * (y + b);
  }
  if (sB >= 0) {
    float wB = twt[2*t + 1];
    f32x4 y = ((const f32x4*)(ybuf + (size_t)sB * DDIM))[d4];
    f32x4 b = ((const f32x4*)(b2 + (size_t)tix[2*t + 1] * DDIM))[d4];
    r += wB * (y + b);
  }
  ((f32x4*)(out + (size_t)t * DDIM))[d4] = r;
}

extern "C" void kernel_launch(void* const* d_in, const int* in_sizes, int n_in,
                              void* d_out, int out_size, void* d_ws, size_t ws_size,
                              hipStream_t stream)
{
  const float* x  = (const float*)d_in[0];
  const unsigned char* pm = (const unsigned char*)d_in[1];
  const float* Wg = (const float*)d_in[2];
  const float* W1 = (const float*)d_in[3];
  const float* b1 = (const float*)d_in[4];
  const float* W2 = (const float*)d_in[5];
  const float* b2 = (const float*)d_in[6];
  float* out = (float*)d_out;
  float* gate_out = out + (size_t)NTOK * DDIM;        // 2097152
  float* lb_out = gate_out + (size_t)NTOK * NEXP;     // 2113536

  char* w = (char*)d_ws;
  int*   ecount   = (int*)(w + 0);
  int*   offs     = (int*)(w + 64);
  int*   fill     = (int*)(w + 128);
  int*   tix      = (int*)(w + 512);                       // 16 KB
  float* twt      = (float*)(w + 512 + 16384);             // 16 KB
  int*   tok_list = (int*)(w + 512 + 32768);               // 16 KB
  int*   slot_of  = (int*)(w + 512 + 49152);               // 16 KB
  uintptr_t p = ((uintptr_t)(w + 512 + 65536) + 255) & ~(uintptr_t)255;
  __bf16* xbf  = (__bf16*)p;                                    // 4 MB
  p += (size_t)NTOK * DDIM * 2;
  __bf16* hbuf = (__bf16*)p;                                    // 33 MB
  p += (size_t)(2 * NTOK + 128) * HDIM * 2;
  float*  ybuf = (float*)p;                                     // 16 MB

  init_kernel<<<1, 64, 0, stream>>>(fill);
  zero_y_kernel<<<(2 * NTOK * DDIM / 4) / 256, 256, 0, stream>>>(ybuf);
  gate_kernel<<<NTOK / 4, 256, 0, stream>>>(x, pm, Wg, gate_out, tix, twt, xbf);
  stats_kernel<<<1, 1024, 0, stream>>>(gate_out, tix, pm, ecount, offs, lb_out);
  compact_kernel<<<NTOK / 256, 256, 0, stream>>>(pm, tix, offs, fill, tok_list, slot_of);
  gemm1_kernel<<<NEXP * (NTOK / 128) * (HDIM / 128), 256, 0, stream>>>(xbf, W1, b1, ecount, offs, tok_list, hbuf);
  gemm2_kernel<<<NEXP * (NTOK / 128) * (DDIM / 128) * KSPLIT, 256, 0, stream>>>(hbuf, W2, ecount, offs, ybuf);
  combine_kernel<<<NTOK, 256, 0, stream>>>(ybuf, slot_of, tix, twt, b2, out);
}

// Round 9
// 286.907 us; speedup vs baseline: 1.2170x; 1.2170x over previous
//
#include <hip/hip_runtime.h>
#include <hip/hip_bf16.h>
#include <stdint.h>

// MoE top-2 of 8 experts.  B=2,T=1024 -> nt=2048 tokens, D=1024, H=4096, E=8.
// d_out layout: out[2*1024*1024] f32 | gate_value[2048*8] f32 | lb_loss[1] f32.
//
// R9: revert GEMM cores to R6 (proven 259us: bf16 preconvert, ring-3 LDS,
// counted vmcnt(4), raw s_barrier).  New: grid-union overlap —
//   preA   = conv_W1 || gate || zero_out      (one dispatch)
//   gemm1u = conv_W2 || gemm1                 (one dispatch, needs +64MiB)
// with a runtime ws_size guard falling back to sequential conv_W2 (w2bf
// aliases w1bf) if the workspace is too small.  ybuf+combine eliminated:
// gemm2 accumulates w*(acc+b2) directly into out via atomics.

#define NTOK 2048
#define DDIM 1024
#define HDIM 4096
#define NEXP 8
#define KSPLIT 2
#define CONVB 1024
#define GATEB (NTOK / 4)
#define ZEROB 512

typedef float  f32x4  __attribute__((ext_vector_type(4)));
typedef __bf16 bf16x8 __attribute__((ext_vector_type(8)));
typedef __bf16 bf16x4 __attribute__((ext_vector_type(4)));

typedef const __attribute__((address_space(1))) void g1_t;
typedef __attribute__((address_space(3))) void l3_t;
__device__ __forceinline__ void gld16(const void* g, void* l) {
  __builtin_amdgcn_global_load_lds((g1_t*)g, (l3_t*)l, 16, 0, 0);
}

// ---------------- init ----------------
__global__ void init_kernel(int* fill) {
  int t = threadIdx.x;
  if (t < NEXP) fill[t] = 0;
}

// ---------------- bodies for fused dispatches ----------------
__device__ __forceinline__ void conv_body(int bid, const float* __restrict__ src,
                                          __bf16* __restrict__ dst, long n8) {
  long i = (long)bid * 256 + threadIdx.x;
  long stride = (long)CONVB * 256;
  for (; i < n8; i += stride) {
    f32x4 a = ((const f32x4*)src)[2 * i];
    f32x4 b = ((const f32x4*)src)[2 * i + 1];
    bf16x8 o;
#pragma unroll
    for (int q = 0; q < 4; ++q) { o[q] = (__bf16)a[q]; o[q + 4] = (__bf16)b[q]; }
    ((bf16x8*)dst)[i] = o;
  }
}

__device__ __forceinline__ void zero_body(int bid, float* __restrict__ y, long n4) {
  long i = (long)bid * 256 + threadIdx.x;
  long stride = (long)ZEROB * 256;
  for (; i < n4; i += stride) ((f32x4*)y)[i] = (f32x4){0.f, 0.f, 0.f, 0.f};
}

__device__ __forceinline__ void gate_body(int bid, const float* __restrict__ x,
                                          const unsigned char* __restrict__ pmask,
                                          const float* __restrict__ Wg,
                                          float* __restrict__ gate_out,
                                          int* __restrict__ tix, float* __restrict__ twt,
                                          __bf16* __restrict__ xbf) {
  int wave = threadIdx.x >> 6, lane = threadIdx.x & 63;
  int t = bid * 4 + wave;   // one wave per token
  const f32x4* x4 = (const f32x4*)(x + (size_t)t * DDIM);
  const f32x4* w4 = (const f32x4*)Wg;
  bf16x4* xb4 = (bf16x4*)(xbf + (size_t)t * DDIM);
  float acc[NEXP];
#pragma unroll
  for (int e = 0; e < NEXP; ++e) acc[e] = 0.f;
#pragma unroll
  for (int i = 0; i < 4; ++i) {
    f32x4 xv = x4[i * 64 + lane];
    bf16x4 xo;
#pragma unroll
    for (int q = 0; q < 4; ++q) xo[q] = (__bf16)xv[q];
    xb4[i * 64 + lane] = xo;
#pragma unroll
    for (int e = 0; e < NEXP; ++e) {
      f32x4 wv = w4[e * 256 + i * 64 + lane];
      acc[e] += xv[0]*wv[0] + xv[1]*wv[1] + xv[2]*wv[2] + xv[3]*wv[3];
    }
  }
#pragma unroll
  for (int e = 0; e < NEXP; ++e) {
    float v = acc[e];
#pragma unroll
    for (int off = 32; off > 0; off >>= 1) v += __shfl_xor(v, off, 64);
    acc[e] = v;
  }
  if (lane == 0) {
    bool pm = pmask[t] != 0;
    float m = acc[0];
#pragma unroll
    for (int e = 1; e < NEXP; ++e) m = fmaxf(m, acc[e]);
    float g[NEXP]; float s = 0.f;
#pragma unroll
    for (int e = 0; e < NEXP; ++e) { g[e] = expf(acc[e] - m); s += g[e]; }
    float inv = 1.f / s;
#pragma unroll
    for (int e = 0; e < NEXP; ++e) g[e] *= inv;
    if (pm) {
#pragma unroll
      for (int e = 0; e < NEXP; ++e) g[e] = 0.f;
    }
    int i1 = 0;
#pragma unroll
    for (int e = 1; e < NEXP; ++e) if (g[e] > g[i1]) i1 = e;
    int i2 = -1;
#pragma unroll
    for (int e = 0; e < NEXP; ++e) if (e != i1 && (i2 < 0 || g[e] > g[i2])) i2 = e;
    float w1 = g[i1], w2 = g[i2], ss = w1 + w2;
    if (ss == 0.f) ss = 1.f;
    w1 /= ss; w2 /= ss;
#pragma unroll
    for (int e = 0; e < NEXP; ++e) gate_out[(size_t)t * NEXP + e] = g[e];
    tix[2*t] = i1; tix[2*t+1] = i2;
    twt[2*t] = w1; twt[2*t+1] = w2;
  }
}

// ---------------- preA: conv_W1 || gate || zero_out ----------------
__global__ __launch_bounds__(256)
void preA_kernel(const float* __restrict__ x, const unsigned char* __restrict__ pmask,
                 const float* __restrict__ Wg, float* __restrict__ gate_out,
                 int* __restrict__ tix, float* __restrict__ twt,
                 __bf16* __restrict__ xbf, const float* __restrict__ W1,
                 __bf16* __restrict__ w1bf, float* __restrict__ out)
{
  int bid = blockIdx.x;
  if (bid < CONVB) { conv_body(bid, W1, w1bf, (long)NEXP * HDIM * DDIM / 8); return; }
  bid -= CONVB;
  if (bid < GATEB) { gate_body(bid, x, pmask, Wg, gate_out, tix, twt, xbf); return; }
  bid -= GATEB;
  zero_body(bid, out, (long)NTOK * DDIM / 4);
}

// ---------------- stats: single-block tree reduce -> ecount/offs/lb ----------------
__global__ __launch_bounds__(1024)
void stats_kernel(const float* __restrict__ gate_out, const int* __restrict__ tix,
                  const unsigned char* __restrict__ pmask,
                  int* __restrict__ ecount, int* __restrict__ offs,
                  float* __restrict__ lb_out)
{
  int tid = threadIdx.x, lane = tid & 63, wv = tid >> 6;   // 16 waves
  float lg[NEXP]; float lt1[NEXP]; int lec[NEXP]; float ln = 0.f;
#pragma unroll
  for (int e = 0; e < NEXP; ++e) { lg[e] = 0.f; lt1[e] = 0.f; lec[e] = 0; }
#pragma unroll
  for (int it = 0; it < NTOK / 1024; ++it) {
    int t = tid + it * 1024;
    f32x4 g0 = ((const f32x4*)(gate_out + (size_t)t * NEXP))[0];
    f32x4 g1 = ((const f32x4*)(gate_out + (size_t)t * NEXP))[1];
    lg[0] += g0[0]; lg[1] += g0[1]; lg[2] += g0[2]; lg[3] += g0[3];
    lg[4] += g1[0]; lg[5] += g1[1]; lg[6] += g1[2]; lg[7] += g1[3];
    if (!pmask[t]) {
      int i1 = tix[2*t], i2 = tix[2*t+1];
      lt1[i1] += 1.f; lec[i1] += 1; lec[i2] += 1; ln += 1.f;
    }
  }
#pragma unroll
  for (int e = 0; e < NEXP; ++e) {
#pragma unroll
    for (int off = 32; off > 0; off >>= 1) {
      lg[e]  += __shfl_xor(lg[e],  off, 64);
      lt1[e] += __shfl_xor(lt1[e], off, 64);
      lec[e] += __shfl_xor(lec[e], off, 64);
    }
  }
#pragma unroll
  for (int off = 32; off > 0; off >>= 1) ln += __shfl_xor(ln, off, 64);
  __shared__ float sg[16][NEXP], st[16][NEXP], sn[16];
  __shared__ int   se[16][NEXP];
  if (lane == 0) {
#pragma unroll
    for (int e = 0; e < NEXP; ++e) { sg[wv][e] = lg[e]; st[wv][e] = lt1[e]; se[wv][e] = lec[e]; }
    sn[wv] = ln;
  }
  __syncthreads();
  if (tid == 0) {
    float G[NEXP] = {0}, T1[NEXP] = {0}; int EC[NEXP] = {0}; float N = 0.f;
    for (int w = 0; w < 16; ++w) {
      N += sn[w];
#pragma unroll
      for (int e = 0; e < NEXP; ++e) { G[e] += sg[w][e]; T1[e] += st[w][e]; EC[e] += se[w][e]; }
    }
    int o = 0;
    for (int e = 0; e < NEXP; ++e) { ecount[e] = EC[e]; offs[e] = o; o += EC[e]; }
    if (N <= 0.f) N = 1.f;
    float lb = 0.f;
    for (int e = 0; e < NEXP; ++e) lb += (T1[e] / N) * (G[e] / N);
    lb_out[0] = (float)NEXP * lb;
  }
}

// ---------------- compaction: ballot-aggregated (1 atomic/wave/expert) ----------------
__global__ __launch_bounds__(256)
void compact_kernel(const unsigned char* __restrict__ pmask, const int* __restrict__ tix,
                    const float* __restrict__ twt, const int* __restrict__ offs,
                    int* __restrict__ fill, int* __restrict__ tok_list,
                    float* __restrict__ wgt_list)
{
  int t = blockIdx.x * 256 + threadIdx.x;
  int lane = threadIdx.x & 63;
  bool pm = pmask[t] != 0;
#pragma unroll
  for (int j = 0; j < 2; ++j) {
    int e = pm ? -1 : tix[2*t + j];
    int pos = -1;
#pragma unroll
    for (int ex = 0; ex < NEXP; ++ex) {
      unsigned long long mask = __ballot(e == ex);
      if (mask) {
        int leader = (int)(__ffsll((long long)mask) - 1);
        int base = 0;
        if (lane == leader) base = atomicAdd(&fill[ex], (int)__popcll(mask));
        base = __shfl(base, leader, 64);
        if (e == ex)
          pos = offs[ex] + base + (int)__popcll(mask & ((1ull << lane) - 1ull));
      }
    }
    if (e >= 0) { tok_list[pos] = t; wgt_list[pos] = twt[2*t + j]; }
  }
}

// ======================= GEMM cores (R6, proven) =======================
// 128x128 tile, BK=32, ring-3 LDS (48KB), counted vmcnt(4), raw s_barrier.
// Swizzle: LDS chunk cs of row r holds data chunk cd = cs^((r>>1)&3);
// linear gload_lds dest, swizzle on global src, undone on fragment read.

__device__ __forceinline__ void gemm1_body(int bid, const __bf16* __restrict__ xbf,
                                           const __bf16* __restrict__ w1bf,
                                           const float* __restrict__ b1,
                                           const int* __restrict__ ecount,
                                           const int* __restrict__ offs,
                                           const int* __restrict__ tok_list,
                                           __bf16* __restrict__ hbuf)
{
  const int NTILE = HDIM / 128;   // 32
  const int MTILE = NTOK / 128;   // 16
  int e = bid / (MTILE * NTILE);
  int rem = bid % (MTILE * NTILE);
  int mt = rem / NTILE, nt = rem % NTILE;
  int cnt = ecount[e];
  if (mt * 128 >= cnt) return;
  int off = offs[e];

  __shared__ __bf16 As[3][128 * 32];
  __shared__ __bf16 Bs[3][128 * 32];

  int tid = threadIdx.x, lane = tid & 63, wave = tid >> 6;
  int wm = wave >> 1, wn = wave & 1;

  const __bf16* aP[2];
  const __bf16* bP[2];
#pragma unroll
  for (int c = 0; c < 2; ++c) {
    int row = c * 64 + (tid >> 2);
    int cd = (tid & 3) ^ ((row >> 1) & 3);
    int mrow = mt * 128 + row;
    int tok = tok_list[off + ((mrow < cnt) ? mrow : 0)];
    aP[c] = xbf + (size_t)tok * DDIM + cd * 8;
    bP[c] = w1bf + (size_t)e * HDIM * DDIM + (size_t)(nt * 128 + row) * DDIM + cd * 8;
  }
  int cg = ((lane >> 4) ^ ((lane >> 1) & 3)) << 3;

  f32x4 acc[4][4];
#pragma unroll
  for (int m = 0; m < 4; ++m)
#pragma unroll
    for (int n = 0; n < 4; ++n) acc[m][n] = (f32x4){0.f, 0.f, 0.f, 0.f};

  const int NIT = DDIM / 32;   // 32
#pragma unroll
  for (int pt = 0; pt < 2; ++pt)
#pragma unroll
    for (int c = 0; c < 2; ++c) {
      gld16(aP[c] + pt * 32, &As[pt][(c * 64 + wave * 16) * 32]);
      gld16(bP[c] + pt * 32, &Bs[pt][(c * 64 + wave * 16) * 32]);
    }

  for (int it = 0; it < NIT; ++it) {
    int cur = it % 3;
    if (it + 1 < NIT) asm volatile("s_waitcnt vmcnt(4)" ::: "memory");
    else              asm volatile("s_waitcnt vmcnt(0)" ::: "memory");
    __builtin_amdgcn_s_barrier();
    __builtin_amdgcn_sched_barrier(0);
    if (it + 2 < NIT) {
      int nb = (it + 2) % 3;
      int k0 = (it + 2) * 32;
#pragma unroll
      for (int c = 0; c < 2; ++c) {
        gld16(aP[c] + k0, &As[nb][(c * 64 + wave * 16) * 32]);
        gld16(bP[c] + k0, &Bs[nb][(c * 64 + wave * 16) * 32]);
      }
    }
    bf16x8 af[4], bfr[4];
#pragma unroll
    for (int m = 0; m < 4; ++m) af[m]  = *(const bf16x8*)&As[cur][(wm*64 + m*16 + (lane & 15)) * 32 + cg];
#pragma unroll
    for (int n = 0; n < 4; ++n) bfr[n] = *(const bf16x8*)&Bs[cur][(wn*64 + n*16 + (lane & 15)) * 32 + cg];
#pragma unroll
    for (int m = 0; m < 4; ++m)
#pragma unroll
      for (int n = 0; n < 4; ++n)
        acc[m][n] = __builtin_amdgcn_mfma_f32_16x16x32_bf16(af[m], bfr[n], acc[m][n], 0, 0, 0);
  }

  // epilogue: +bias, relu, bf16 store
#pragma unroll
  for (int n = 0; n < 4; ++n) {
    int col = nt * 128 + wn * 64 + n * 16 + (lane & 15);
    float bias = b1[e * HDIM + col];
#pragma unroll
    for (int m = 0; m < 4; ++m) {
#pragma unroll
      for (int j = 0; j < 4; ++j) {
        int mr = mt * 128 + wm * 64 + m * 16 + ((lane >> 4) << 2) + j;
        if (mr < cnt) {
          float v = fmaxf(acc[m][n][j] + bias, 0.f);
          hbuf[(size_t)(off + mr) * HDIM + col] = (__bf16)v;
        }
      }
    }
  }
}

// union: conv_W2 || gemm1
__global__ __launch_bounds__(256)
void gemm1u_kernel(const __bf16* __restrict__ xbf, const __bf16* __restrict__ w1bf,
                   const float* __restrict__ b1, const int* __restrict__ ecount,
                   const int* __restrict__ offs, const int* __restrict__ tok_list,
                   __bf16* __restrict__ hbuf, const float* __restrict__ W2,
                   __bf16* __restrict__ w2bf)
{
  if (blockIdx.x < CONVB) { conv_body(blockIdx.x, W2, w2bf, (long)NEXP * DDIM * HDIM / 8); return; }
  gemm1_body(blockIdx.x - CONVB, xbf, w1bf, b1, ecount, offs, tok_list, hbuf);
}

__global__ __launch_bounds__(256)
void gemm1_kernel(const __bf16* __restrict__ xbf, const __bf16* __restrict__ w1bf,
                  const float* __restrict__ b1, const int* __restrict__ ecount,
                  const int* __restrict__ offs, const int* __restrict__ tok_list,
                  __bf16* __restrict__ hbuf)
{
  gemm1_body(blockIdx.x, xbf, w1bf, b1, ecount, offs, tok_list, hbuf);
}

__global__ __launch_bounds__(256)
void conv_kernel(const float* __restrict__ src, __bf16* __restrict__ dst, long n8)
{
  conv_body(blockIdx.x, src, dst, n8);
}

// ---------------- GEMM2 (K-split): out[tok,:] += w*(h·W2^T + b2) directly ----------------
__global__ __launch_bounds__(256)
void gemm2_kernel(const __bf16* __restrict__ hbuf, const __bf16* __restrict__ w2bf,
                  const float* __restrict__ b2, const int* __restrict__ ecount,
                  const int* __restrict__ offs, const int* __restrict__ tok_list,
                  const float* __restrict__ wgt_list, float* __restrict__ out)
{
  const int NTILE = DDIM / 128;   // 8
  const int MTILE = NTOK / 128;   // 16
  int bid = blockIdx.x;
  int e = bid / (MTILE * NTILE * KSPLIT);
  int rem = bid % (MTILE * NTILE * KSPLIT);
  int mt = rem / (NTILE * KSPLIT);
  int rem2 = rem % (NTILE * KSPLIT);
  int nt = rem2 / KSPLIT, kc = rem2 % KSPLIT;
  int cnt = ecount[e];
  if (mt * 128 >= cnt) return;
  int off = offs[e];

  __shared__ __bf16 As[3][128 * 32];
  __shared__ __bf16 Bs[3][128 * 32];

  int tid = threadIdx.x, lane = tid & 63, wave = tid >> 6;
  int wm = wave >> 1, wn = wave & 1;

  const __bf16* aP[2];
  const __bf16* bP[2];
#pragma unroll
  for (int c = 0; c < 2; ++c) {
    int row = c * 64 + (tid >> 2);
    int cd = (tid & 3) ^ ((row >> 1) & 3);
    aP[c] = hbuf + (size_t)(off + mt * 128 + row) * HDIM + cd * 8;
    bP[c] = w2bf + (size_t)e * DDIM * HDIM + (size_t)(nt * 128 + row) * HDIM + cd * 8;
  }
  int cg = ((lane >> 4) ^ ((lane >> 1) & 3)) << 3;

  f32x4 acc[4][4];
#pragma unroll
  for (int m = 0; m < 4; ++m)
#pragma unroll
    for (int n = 0; n < 4; ++n) acc[m][n] = (f32x4){0.f, 0.f, 0.f, 0.f};

  const int KCH = HDIM / KSPLIT;      // 2048
  const int NIT = KCH / 32;           // 64
  int kbeg = kc * KCH;
#pragma unroll
  for (int pt = 0; pt < 2; ++pt)
#pragma unroll
    for (int c = 0; c < 2; ++c) {
      gld16(aP[c] + kbeg + pt * 32, &As[pt][(c * 64 + wave * 16) * 32]);
      gld16(bP[c] + kbeg + pt * 32, &Bs[pt][(c * 64 + wave * 16) * 32]);
    }

  for (int it = 0; it < NIT; ++it) {
    int cur = it % 3;
    if (it + 1 < NIT) asm volatile("s_waitcnt vmcnt(4)" ::: "memory");
    else              asm volatile("s_waitcnt vmcnt(0)" ::: "memory");
    __builtin_amdgcn_s_barrier();
    __builtin_amdgcn_sched_barrier(0);
    if (it + 2 < NIT) {
      int nb = (it + 2) % 3;
      int k0 = kbeg + (it + 2) * 32;
#pragma unroll
      for (int c = 0; c < 2; ++c) {
        gld16(aP[c] + k0, &As[nb][(c * 64 + wave * 16) * 32]);
        gld16(bP[c] + k0, &Bs[nb][(c * 64 + wave * 16) * 32]);
      }
    }
    bf16x8 af[4], bfr[4];
#pragma unroll
    for (int m = 0; m < 4; ++m) af[m]  = *(const bf16x8*)&As[cur][(wm*64 + m*16 + (lane & 15)) * 32 + cg];
#pragma unroll
    for (int n = 0; n < 4; ++n) bfr[n] = *(const bf16x8*)&Bs[cur][(wn*64 + n*16 + (lane & 15)) * 32 + cg];
#pragma unroll
    for (int m = 0; m < 4; ++m)
#pragma unroll
      for (int n = 0; n < 4; ++n)
        acc[m][n] = __builtin_amdgcn_mfma_f32_16x16x32_bf16(af[m], bfr[n], acc[m][n], 0, 0, 0);
  }

  // epilogue: atomic accumulate w*(acc [+ b2 on kc==0]) directly into out
  float b2v[4];
#pragma unroll
  for (int n = 0; n < 4; ++n) {
    int col = nt * 128 + wn * 64 + n * 16 + (lane & 15);
    b2v[n] = (kc == 0) ? b2[e * DDIM + col] : 0.f;
  }
#pragma unroll
  for (int m = 0; m < 4; ++m) {
#pragma unroll
    for (int j = 0; j < 4; ++j) {
      int mr = mt * 128 + wm * 64 + m * 16 + ((lane >> 4) << 2) + j;
      if (mr >= cnt) continue;
      int slot = off + mr;
      int tok = tok_list[slot];
      float w = wgt_list[slot];
      float* obase = out + (size_t)tok * DDIM;
#pragma unroll
      for (int n = 0; n < 4; ++n) {
        int col = nt * 128 + wn * 64 + n * 16 + (lane & 15);
        atomicAdd(obase + col, w * (acc[m][n][j] + b2v[n]));
      }
    }
  }
}

extern "C" void kernel_launch(void* const* d_in, const int* in_sizes, int n_in,
                              void* d_out, int out_size, void* d_ws, size_t ws_size,
                              hipStream_t stream)
{
  const float* x  = (const float*)d_in[0];
  const unsigned char* pm = (const unsigned char*)d_in[1];
  const float* Wg = (const float*)d_in[2];
  const float* W1 = (const float*)d_in[3];
  const float* b1 = (const float*)d_in[4];
  const float* W2 = (const float*)d_in[5];
  const float* b2 = (const float*)d_in[6];
  float* out = (float*)d_out;
  float* gate_out = out + (size_t)NTOK * DDIM;        // 2097152
  float* lb_out = gate_out + (size_t)NTOK * NEXP;     // 2113536

  char* w = (char*)d_ws;
  int*   ecount   = (int*)(w + 0);
  int*   offs     = (int*)(w + 64);
  int*   fill     = (int*)(w + 128);
  int*   tix      = (int*)(w + 512);                       // 16 KB
  float* twt      = (float*)(w + 512 + 16384);             // 16 KB
  int*   tok_list = (int*)(w + 512 + 32768);               // 16 KB
  float* wgt_list = (float*)(w + 512 + 49152);             // 16 KB
  uintptr_t p = ((uintptr_t)(w + 512 + 65536) + 255) & ~(uintptr_t)255;
  __bf16* xbf  = (__bf16*)p;                                    // 4 MB
  p += (size_t)NTOK * DDIM * 2;
  __bf16* w1bf = (__bf16*)p;                                    // 64 MB
  p += (size_t)NEXP * HDIM * DDIM * 2;
  __bf16* hbuf = (__bf16*)p;                                    // 33 MB
  p += (size_t)(2 * NTOK + 128) * HDIM * 2;
  // overlap path wants a second weight buffer after hbuf:
  __bf16* w2bf_sep = (__bf16*)p;
  size_t need = (size_t)((char*)(w2bf_sep + (size_t)NEXP * DDIM * HDIM) - w);
  bool overlap = (ws_size >= need);
  __bf16* w2bf = overlap ? w2bf_sep : w1bf;   // seq path reuses w1bf region

  init_kernel<<<1, 64, 0, stream>>>(fill);
  preA_kernel<<<CONVB + GATEB + ZEROB, 256, 0, stream>>>(x, pm, Wg, gate_out, tix, twt, xbf, W1, w1bf, out);
  stats_kernel<<<1, 1024, 0, stream>>>(gate_out, tix, pm, ecount, offs, lb_out);
  compact_kernel<<<NTOK / 256, 256, 0, stream>>>(pm, tix, twt, offs, fill, tok_list, wgt_list);
  if (overlap) {
    gemm1u_kernel<<<CONVB + NEXP * (NTOK / 128) * (HDIM / 128), 256, 0, stream>>>(
        xbf, w1bf, b1, ecount, offs, tok_list, hbuf, W2, w2bf);
  } else {
    gemm1_kernel<<<NEXP * (NTOK / 128) * (HDIM / 128), 256, 0, stream>>>(
        xbf, w1bf, b1, ecount, offs, tok_list, hbuf);
    conv_kernel<<<CONVB, 256, 0, stream>>>(W2, w2bf, (long)NEXP * DDIM * HDIM / 8);
  }
  gemm2_kernel<<<NEXP * (NTOK / 128) * (DDIM / 128) * KSPLIT, 256, 0, stream>>>(
      hbuf, w2bf, b2, ecount, offs, tok_list, wgt_list, out);
}